// Round 1
// baseline (1199.643 us; speedup 1.0000x reference)
//
#include <hip/hip_runtime.h>

// GNODecoder round 23: MFMA rewrite of the edge-MLP inner layers.
// Ledger: 8 VALU edge-kernel structures all plateau 1.13-1.35 ms, VALUBusy
// 21-26%. Diagnosis: B-operand delivery via s_load -- 48 KB weight working
// set thrashes the scalar cache, and ds_read(A)/s_load(B) share lgkmcnt
// (SMEM is out-of-order -> forced lgkmcnt(0) drains). Exit: GEMM2 (64x64)
// and GEMM3 (64x128) on v_mfma_f32_16x16x32_f16; weights pre-packed f16,
// transposed [n][k], XOR-swizzled by a prep kernel, staged 24 KB -> LDS per
// block. L0 (K=6) stays exact fp32 VALU (tiny scalar set, sL1-resident).
// A-fragments are own-m-tile-only -> 2 barriers/tile. fp32 accumulate,
// gather/scatter/mean/proj unchanged fp32. Predicted fused 1130 -> ~250 us.

#define BLOCK 256

typedef _Float16 half8 __attribute__((ext_vector_type(8)));
typedef float f32x4 __attribute__((ext_vector_type(4)));

// LDS byte layout (fused kernel):
//   [0,     8192)  hT   : [64 rows][8 chunks of 16B] f16, chunk ^= (row&7)
//   [8192, 16384)  W1T  : [64 n][64 k] f16, same swizzle
//   [16384,32768)  W2T  : [128 n][64 k] f16, same swizzle
//   [32768, ... )  sacc : [QB][129] f32

__device__ __forceinline__ float gelu_f(float x) {
    // jax.nn.gelu default (approximate=True, tanh form)
    float x3 = x * x * x;
    float t  = 0.7978845608028654f * fmaf(0.044715f, x3, x);
    float e  = __expf(2.0f * t);
    float r  = __builtin_amdgcn_rcpf(e + 1.0f);
    return 0.5f * x * (1.0f + (1.0f - 2.0f * r));
}

// ---------- sort machinery (proven) ----------

__global__ void hist_kernel(const int* __restrict__ dst, int* __restrict__ hist, int E) {
    int e = blockIdx.x * blockDim.x + threadIdx.x;
    if (e < E) atomicAdd(&hist[dst[e]], 1);
}

__global__ __launch_bounds__(1024) void scan_kernel(const int* __restrict__ hist,
                                                    int* __restrict__ start, int n) {
    __shared__ int wsum[16];
    __shared__ int woff[16];
    int tid = threadIdx.x;
    int lane = tid & 63, wid = tid >> 6;
    int carry = 0;  // meaningful on tid 0 only
    for (int base = 0; base < n; base += 1024) {
        int i = base + tid;
        int v = (i < n) ? hist[i] : 0;
        int incl = v;
#pragma unroll
        for (int off = 1; off < 64; off <<= 1) {
            int t = __shfl_up(incl, off, 64);
            if (lane >= off) incl += t;
        }
        if (lane == 63) wsum[wid] = incl;
        __syncthreads();
        if (tid == 0) {
            int acc = carry;
#pragma unroll
            for (int w = 0; w < 16; ++w) { woff[w] = acc; acc += wsum[w]; }
            carry = acc;
        }
        __syncthreads();
        if (i < n) start[i] = woff[wid] + incl - v;
        __syncthreads();
    }
    if (threadIdx.x == 0) start[n] = carry;
}

__global__ void scatter_kernel(const int* __restrict__ dst, const int* __restrict__ src,
                               const int* __restrict__ start, int* __restrict__ cursor,
                               int* __restrict__ dsts, int* __restrict__ srcs, int E) {
    int e = blockIdx.x * blockDim.x + threadIdx.x;
    if (e >= E) return;
    int d = dst[e];
    int pos = start[d] + atomicAdd(&cursor[d], 1);
    dsts[pos] = d;
    srcs[pos] = src[e];
}

// ---------- weight prep: f16, transposed [n][k], XOR-swizzled image ----------
// img bytes: W1T at [0,8192), W2T at [8192,24576).
// element (n,k): byte = base + n*128 + (((k>>3) ^ (n&7))*16) + (k&7)*2

__global__ void wprep_kernel(const float* __restrict__ W1,
                             const float* __restrict__ W2,
                             char* __restrict__ img) {
    union { _Float16 h[8]; uint4 u; } cv;
    for (int task = threadIdx.x; task < 1536; task += 256) {
        bool isW2 = task >= 512;
        int id = isW2 ? task - 512 : task;
        int n = id >> 3, kc = id & 7;
        const float* W = isW2 ? W2 : W1;
        int N = isW2 ? 128 : 64;
#pragma unroll
        for (int j = 0; j < 8; ++j) cv.h[j] = (_Float16)W[(kc * 8 + j) * N + n];
        *(uint4*)(img + (isW2 ? 8192 : 0) + n * 128 + ((kc ^ (n & 7)) * 16)) = cv.u;
    }
}

// ---------- fused: L0 VALU fp32, GEMM2/GEMM3 via mfma f16 ----------

template <int QB, bool FUSED_PROJ>
__global__ __launch_bounds__(BLOCK, 3) void fused_kernel(
    const float* __restrict__ rndata,   // [NL,128]
    const float* __restrict__ qpos,     // [NQ,3]
    const float* __restrict__ lpos,     // [NL,3]
    const int*   __restrict__ dsts,     // [E] sorted by dst
    const int*   __restrict__ srcs,     // [E]
    const int*   __restrict__ start,    // [NQ+1]
    const float* __restrict__ W0, const float* __restrict__ b0,
    const float* __restrict__ b1, const float* __restrict__ b2,
    const uint4* __restrict__ wimg,     // 24576 B packed W1T/W2T image
    const float* __restrict__ P0, const float* __restrict__ pb0,
    const float* __restrict__ P1, const float* __restrict__ pb1,
    float* __restrict__ agg,            // [NQ,128] mean (path A)
    float* __restrict__ out,            // [NQ,4]   (FUSED_PROJ)
    int nq)
{
    extern __shared__ char smemc[];
    float* sacc = (float*)(smemc + 32768);
    const int tid = threadIdx.x;

    // stage weight image -> LDS [8192, 32768)
    {
        uint4* wdst = (uint4*)(smemc + 8192);
        for (int i = tid; i < 1536; i += BLOCK) wdst[i] = wimg[i];
    }
    for (int i = tid; i < QB * 129; i += BLOCK) sacc[i] = 0.f;

    const int q0   = blockIdx.x * QB;
    const int qend = min(q0 + QB, nq);
    const int e0 = start[q0], e1 = start[qend];
    const int ntiles = (e1 - e0 + 63) >> 6;

    const int m   = tid & 63;                                  // lane / edge row
    const int wid = tid >> 6;                                  // wave = m-tile
    const int wn1 = __builtin_amdgcn_readfirstlane(wid * 16);  // L0 n-slice
    const int col = m & 15;
    const int g   = m >> 4;                                    // 0..3
    const int arow  = wid * 16 + col;                          // A-frag row
    const int aoff0 = arow * 128 + (((0 + g) ^ (arow & 7)) * 16);  // ks=0
    const int aoff1 = arow * 128 + (((4 + g) ^ (arow & 7)) * 16);  // ks=1

    float b1v[4], b2v[8];
#pragma unroll
    for (int nt = 0; nt < 4; ++nt) b1v[nt] = b1[nt * 16 + col];
#pragma unroll
    for (int nt = 0; nt < 8; ++nt) b2v[nt] = b2[nt * 16 + col];

    __syncthreads();  // weights staged + sacc zeroed

    for (int t = 0; t < ntiles; ++t) {
        const int ebase = e0 + (t << 6);
        int  e     = ebase + m;
        bool valid = e < e1;
        int  d = valid ? dsts[e] : q0;
        int  s = valid ? srcs[e] : 0;
        float pin[6];
        {
            const float* pq = qpos + d * 3;
            pin[0] = pq[0]; pin[1] = pq[1]; pin[2] = pq[2];
            const float* pl = lpos + s * 3;
            pin[3] = pl[0]; pin[4] = pl[1]; pin[5] = pl[2];
        }

        // ---- L0 (exact fp32, s_load W0: 96 floats, sL1-resident) ----
        float C0[16];
#pragma unroll
        for (int j = 0; j < 16; ++j) C0[j] = b0[wn1 + j];
#pragma unroll
        for (int k = 0; k < 6; ++k) {
            float a = pin[k];
#pragma unroll
            for (int j = 0; j < 16; ++j)
                C0[j] = fmaf(a, W0[k * 64 + wn1 + j], C0[j]);
        }

        __syncthreads();  // barrier A: prev tile's hT A-reads done

        // h0 = gelu(C0) -> f16, two swizzled 16B chunks (conflict-free)
        {
            union { _Float16 h[8]; uint4 u; } u0, u1;
#pragma unroll
            for (int j = 0; j < 8; ++j) u0.h[j] = (_Float16)gelu_f(C0[j]);
#pragma unroll
            for (int j = 0; j < 8; ++j) u1.h[j] = (_Float16)gelu_f(C0[8 + j]);
            const int c0 = wid * 2;
            *(uint4*)(smemc + m * 128 + (((c0    ) ^ (m & 7)) * 16)) = u0.u;
            *(uint4*)(smemc + m * 128 + (((c0 + 1) ^ (m & 7)) * 16)) = u1.u;
        }
        __syncthreads();  // barrier B: h0 ready (col-sliced across waves)

        // ---- GEMM2: h0[64x64] @ W1[64x64] ----
        half8 a0 = *(const half8*)(smemc + aoff0);
        half8 a1 = *(const half8*)(smemc + aoff1);
        f32x4 c1[4];
#pragma unroll
        for (int nt = 0; nt < 4; ++nt) {
            const int  nrow = nt * 16 + col;
            const char* wb  = smemc + 8192 + nrow * 128;
            half8 bb0 = *(const half8*)(wb + (((0 + g) ^ (nrow & 7)) * 16));
            half8 bb1 = *(const half8*)(wb + (((4 + g) ^ (nrow & 7)) * 16));
            f32x4 acc = {b1v[nt], b1v[nt], b1v[nt], b1v[nt]};
            acc = __builtin_amdgcn_mfma_f32_16x16x32_f16(a0, bb0, acc, 0, 0, 0);
            acc = __builtin_amdgcn_mfma_f32_16x16x32_f16(a1, bb1, acc, 0, 0, 0);
            c1[nt] = acc;
        }

        // h1 = gelu(c1) -> same hT rows. Own m-tile rows only; DS is in-order
        // per wave and other waves never touch these rows -> no barrier.
#pragma unroll
        for (int nt = 0; nt < 4; ++nt) {
#pragma unroll
            for (int i = 0; i < 4; ++i) {
                const int row = wid * 16 + g * 4 + i;
                const int ch  = nt * 16 + col;
                *(_Float16*)(smemc + row * 128 + (((ch >> 3) ^ (row & 7)) * 16)
                             + (ch & 7) * 2) = (_Float16)gelu_f(c1[nt][i]);
            }
        }

        // ---- GEMM3: h1[64x64] @ W2[64x128] ----
        half8 a2 = *(const half8*)(smemc + aoff0);
        half8 a3 = *(const half8*)(smemc + aoff1);
        f32x4 c2[8];
#pragma unroll
        for (int nt = 0; nt < 8; ++nt) {
            const int  nrow = nt * 16 + col;
            const char* wb  = smemc + 16384 + nrow * 128;
            half8 bb0 = *(const half8*)(wb + (((0 + g) ^ (nrow & 7)) * 16));
            half8 bb1 = *(const half8*)(wb + (((4 + g) ^ (nrow & 7)) * 16));
            f32x4 acc = {b2v[nt], b2v[nt], b2v[nt], b2v[nt]};
            acc = __builtin_amdgcn_mfma_f32_16x16x32_f16(a2, bb0, acc, 0, 0, 0);
            acc = __builtin_amdgcn_mfma_f32_16x16x32_f16(a3, bb1, acc, 0, 0, 0);
            c2[nt] = acc;
        }

        // ---- epilogue: k2 * r -> sacc (C/D frag: col=lane&15, row=(g*4+i)) ----
#pragma unroll
        for (int i = 0; i < 4; ++i) {
            const int erow = wid * 16 + g * 4 + i;
            const int eidx = ebase + erow;
            if (eidx < e1) {
                const int dd = dsts[eidx];
                const int ss = srcs[eidx];
                const float* rr = rndata + (size_t)ss * 128 + col;
                float*       sr = sacc + (dd - q0) * 129 + col;
#pragma unroll
                for (int nt = 0; nt < 8; ++nt)
                    atomicAdd(&sr[nt * 16], c2[nt][i] * rr[nt * 16]);
            }
        }
        // next tile's barrier A orders these reads/atomics vs hT overwrite
    }
    __syncthreads();  // last tile's atomics visible

    if (!FUSED_PROJ) {
        for (int idx = tid; idx < QB * 128; idx += BLOCK) {
            int ql = idx >> 7, c = idx & 127;
            int q  = q0 + ql;
            if (q < qend) {
                float deg = (float)(start[q + 1] - start[q]);
                agg[(size_t)q * 128 + c] = sacc[ql * 129 + c] / fmaxf(deg, 1.f);
            }
        }
    } else {
        if (tid < QB) {
            int q = q0 + tid;
            if (q < nq) {
                float deg = (float)(start[q + 1] - start[q]);
                float inv = 1.0f / fmaxf(deg, 1.f);
                const float* aq = &sacc[tid * 129];
                float o0 = pb1[0], o1 = pb1[1], o2 = pb1[2], o3 = pb1[3];
#pragma unroll 1
                for (int jj = 0; jj < 256; jj += 8) {
                    float acc[8];
#pragma unroll
                    for (int u = 0; u < 8; ++u) acc[u] = pb0[jj + u];
#pragma unroll
                    for (int i = 0; i < 128; ++i) {
                        float av = aq[i] * inv;
#pragma unroll
                        for (int u = 0; u < 8; ++u)
                            acc[u] = fmaf(av, P0[i * 256 + jj + u], acc[u]);
                    }
#pragma unroll
                    for (int u = 0; u < 8; ++u) {
                        float h = gelu_f(acc[u]);
                        o0 = fmaf(h, P1[(jj + u) * 4 + 0], o0);
                        o1 = fmaf(h, P1[(jj + u) * 4 + 1], o1);
                        o2 = fmaf(h, P1[(jj + u) * 4 + 2], o2);
                        o3 = fmaf(h, P1[(jj + u) * 4 + 3], o3);
                    }
                }
                float4* o4 = (float4*)(out + (size_t)q * 4);
                *o4 = make_float4(o0, o1, o2, o3);
            }
        }
    }
}

// ---------- projection: plain r7/r9 kernel (proven ~270 us) ----------

__global__ __launch_bounds__(256) void proj_kernel(
    const float* __restrict__ agg,      // [NQ,128] mean
    const float* __restrict__ P0, const float* __restrict__ pb0,
    const float* __restrict__ P1, const float* __restrict__ pb1,
    float* __restrict__ out, int nq)
{
    int q = blockIdx.x * blockDim.x + threadIdx.x;
    if (q >= nq) return;

    float a[128];
    const float4* ag4 = (const float4*)(agg + (size_t)q * 128);
#pragma unroll
    for (int i = 0; i < 32; ++i) {
        float4 v = ag4[i];
        a[4 * i + 0] = v.x; a[4 * i + 1] = v.y;
        a[4 * i + 2] = v.z; a[4 * i + 3] = v.w;
    }

    float o0 = pb1[0], o1 = pb1[1], o2 = pb1[2], o3 = pb1[3];
#pragma unroll 1
    for (int jj = 0; jj < 256; jj += 8) {
        float acc[8];
#pragma unroll
        for (int u = 0; u < 8; ++u) acc[u] = pb0[jj + u];
#pragma unroll
        for (int i = 0; i < 128; ++i) {
            float av = a[i];
#pragma unroll
            for (int u = 0; u < 8; ++u)
                acc[u] = fmaf(av, P0[i * 256 + jj + u], acc[u]);
        }
#pragma unroll
        for (int u = 0; u < 8; ++u) {
            float h = gelu_f(acc[u]);
            o0 = fmaf(h, P1[(jj + u) * 4 + 0], o0);
            o1 = fmaf(h, P1[(jj + u) * 4 + 1], o1);
            o2 = fmaf(h, P1[(jj + u) * 4 + 2], o2);
            o3 = fmaf(h, P1[(jj + u) * 4 + 3], o3);
        }
    }
    float4* o4 = (float4*)(out + (size_t)q * 4);
    *o4 = make_float4(o0, o1, o2, o3);
}

extern "C" void kernel_launch(void* const* d_in, const int* in_sizes, int n_in,
                              void* d_out, int out_size, void* d_ws, size_t ws_size,
                              hipStream_t stream)
{
    const float* rndata = (const float*)d_in[0];
    const float* qpos   = (const float*)d_in[1];
    const float* lpos   = (const float*)d_in[2];
    const int*   dst    = (const int*)d_in[3];
    const int*   src    = (const int*)d_in[4];
    const float* W0  = (const float*)d_in[5];
    const float* b0  = (const float*)d_in[6];
    const float* W1  = (const float*)d_in[7];
    const float* b1  = (const float*)d_in[8];
    const float* W2  = (const float*)d_in[9];
    const float* b2  = (const float*)d_in[10];
    const float* P0  = (const float*)d_in[11];
    const float* pb0 = (const float*)d_in[12];
    const float* P1  = (const float*)d_in[13];
    const float* pb1 = (const float*)d_in[14];

    int nq = in_sizes[1] / 3;
    int E  = in_sizes[3];

    // ws layout: [agg nq*128 (path A)] [hist] [cursor] [start] [dsts] [srcs] [wimg]
    size_t agg_bytes  = (size_t)nq * 128 * sizeof(float);
    size_t sort_bytes = 0;
    {
        size_t o = 0;
        o += ((size_t)nq * sizeof(int) + 15) & ~(size_t)15;
        o += ((size_t)nq * sizeof(int) + 15) & ~(size_t)15;
        o += ((size_t)(nq + 1) * sizeof(int) + 15) & ~(size_t)15;
        o += ((size_t)E * sizeof(int) + 15) & ~(size_t)15;
        o += ((size_t)E * sizeof(int) + 15) & ~(size_t)15;
        o += 24576;  // packed f16 weight image
        sort_bytes = o;
    }
    bool path_a = (agg_bytes + sort_bytes) <= ws_size;

    size_t off = path_a ? agg_bytes : 0;
    auto alloc = [&](size_t bytes) {
        void* p = (char*)d_ws + off;
        off += (bytes + 15) & ~(size_t)15;
        return p;
    };
    float* agg   = (float*)d_ws;  // path A only
    int* hist    = (int*)alloc((size_t)nq * sizeof(int));
    int* cursor  = (int*)alloc((size_t)nq * sizeof(int));
    int* start   = (int*)alloc((size_t)(nq + 1) * sizeof(int));
    int* dsts    = (int*)alloc((size_t)E * sizeof(int));
    int* srcs    = (int*)alloc((size_t)E * sizeof(int));
    uint4* wimg  = (uint4*)alloc(24576);

    size_t histpad = ((size_t)nq * sizeof(int) + 15) & ~(size_t)15;
    hipMemsetAsync(hist, 0, 2 * histpad, stream);

    wprep_kernel<<<1, 256, 0, stream>>>(W1, W2, (char*)wimg);
    hist_kernel<<<(E + 255) / 256, 256, 0, stream>>>(dst, hist, E);
    scan_kernel<<<1, 1024, 0, stream>>>(hist, start, nq);
    scatter_kernel<<<(E + 255) / 256, 256, 0, stream>>>(dst, src, start, cursor, dsts, srcs, E);

    constexpr int    QB   = 32;
    constexpr size_t SMEM = 32768 + (size_t)QB * 129 * 4;  // 49,280 B -> 3 blocks/CU
    int nb = (nq + QB - 1) / QB;

    if (path_a) {
        fused_kernel<QB, false><<<nb, BLOCK, SMEM, stream>>>(
            rndata, qpos, lpos, dsts, srcs, start,
            W0, b0, b1, b2, wimg, P0, pb0, P1, pb1, agg, nullptr, nq);
        proj_kernel<<<(nq + 255) / 256, 256, 0, stream>>>(
            agg, P0, pb0, P1, pb1, (float*)d_out, nq);
    } else {
        fused_kernel<QB, true><<<nb, BLOCK, SMEM, stream>>>(
            rndata, qpos, lpos, dsts, srcs, start,
            W0, b0, b1, b2, wimg, P0, pb0, P1, pb1, nullptr, (float*)d_out, nq);
    }
}